// Round 3
// baseline (1709.157 us; speedup 1.0000x reference)
//
#include <hip/hip_runtime.h>

// ---------------------------------------------------------------------------
// MultiHeadsAttention: X[4,2048,1024] -> ctx[4,2048,1024], q[4,16,2048,64],
// k[4,16,2048,64] (q,k post-RoPE). fp32 in/out, bf16 MFMA internally.
// ---------------------------------------------------------------------------

#define B_  4
#define S_  2048
#define H_  16
#define D_  64
#define HID 1024
#define M_  (B_ * S_)          // 8192

typedef __attribute__((ext_vector_type(8))) short    bf16x8;
typedef __attribute__((ext_vector_type(4))) float    f32x4;
typedef __attribute__((ext_vector_type(4))) unsigned short u16x4;
typedef __attribute__((ext_vector_type(8))) unsigned short u16x8;

__device__ __forceinline__ unsigned short f2bf(float f) {
    union { float f; unsigned u; } v; v.f = f;
    unsigned r = v.u + 0x7fffu + ((v.u >> 16) & 1u);
    return (unsigned short)(r >> 16);
}
__device__ __forceinline__ unsigned short f2bf_trunc(float f) {
    union { float f; unsigned u; } v; v.f = f;
    return (unsigned short)(v.u >> 16);
}

__device__ __forceinline__ void async16(const unsigned short* g, unsigned short* l) {
    __builtin_amdgcn_global_load_lds(
        (const __attribute__((address_space(1))) void*)g,
        (__attribute__((address_space(3))) void*)l, 16, 0, 0);
}

// ---------------------------------------------------------------------------
// Kernel 0: RoPE tables -> d_out ctx region (overwritten later by attn).
// cosT[s*64+d], sinT[s*64+d]
// ---------------------------------------------------------------------------
__global__ __launch_bounds__(256) void rope_table_kernel(float* __restrict__ tab)
{
    int i = blockIdx.x * 256 + threadIdx.x;     // 0 .. 131071
    int s = i >> 6, d = i & 63;
    const float NEG_LN1E4_32 = -0.28782313662425576f;  // -ln(10000)/32
    float freq = __expf(NEG_LN1E4_32 * (float)(d >> 1));
    float ang = (float)s * freq;
    tab[i]          = cosf(ang);
    tab[131072 + i] = sinf(ang);
}

// ---------------------------------------------------------------------------
// Kernel 1: cast X fp32 -> bf16
// ---------------------------------------------------------------------------
__global__ __launch_bounds__(256) void cast_x_kernel(
    const float* __restrict__ X, unsigned short* __restrict__ Xb)
{
    int i = (blockIdx.x * 256 + threadIdx.x) * 4;
    float4 v = *(const float4*)(X + i);
    u16x4 o;
    o[0] = f2bf(v.x); o[1] = f2bf(v.y); o[2] = f2bf(v.z); o[3] = f2bf(v.w);
    *(u16x4*)(Xb + i) = o;
}

// ---------------------------------------------------------------------------
// Kernel 2: transpose+cast W[k][n] fp32 -> Wt[n][k] bf16  (z selects q/k/v)
// ---------------------------------------------------------------------------
__global__ __launch_bounds__(256) void cast_wt_kernel(
    const float* __restrict__ Wq, const float* __restrict__ Wk,
    const float* __restrict__ Wv, unsigned short* __restrict__ Wt)
{
    __shared__ float tile[64][65];
    int z = blockIdx.z;
    const float* W = (z == 0) ? Wq : ((z == 1) ? Wk : Wv);
    unsigned short* out = Wt + (size_t)z * HID * HID;
    int n0 = blockIdx.x * 64, k0 = blockIdx.y * 64;
    int tx = threadIdx.x & 63, ty0 = threadIdx.x >> 6;
    for (int i = 0; i < 16; i++) {
        int ty = ty0 * 16 + i;
        tile[ty][tx] = W[(size_t)(k0 + ty) * HID + n0 + tx];
    }
    __syncthreads();
    for (int i = 0; i < 16; i++) {
        int ty = ty0 * 16 + i;
        out[(size_t)(n0 + ty) * HID + k0 + tx] = f2bf(tile[tx][ty]);
    }
}

// ---------------------------------------------------------------------------
// Kernel 3: QKV GEMM, m97 structure: 128x128 tile, BK=32, global_load_lds
// staging, 4 waves each computing 64x64 (4x4 fragments of 16x16x32 MFMA).
// Epilogue fuses bias + table-RoPE.
// grid (HID/128 = 8 fast -> XCD = n-block, M/128 = 64, 3).
// __launch_bounds__(256,2): 256-VGPR budget; round-2's missing 2nd arg made
// the allocator spill acc[4][4] to scratch (3 GB HBM writes, MfmaUtil 2.3%).
// ---------------------------------------------------------------------------
#define BM 128
#define BN 128
#define BKQ 32

__global__ __launch_bounds__(256, 2) void qkv_gemm_kernel(
    const unsigned short* __restrict__ Xb, const unsigned short* __restrict__ Wt,
    const float* __restrict__ bq, const float* __restrict__ bk,
    const float* __restrict__ bv,
    float* out,                         // d_out base (also holds rope tables)
    unsigned short* __restrict__ Qb, unsigned short* __restrict__ Kb,
    unsigned short* __restrict__ Vb)
{
    __shared__ unsigned short As[BM * BKQ];   // row-major [128][32], unpadded
    __shared__ unsigned short Bs[BN * BKQ];   // (global_load_lds layout rule)

    const size_t Q_OFF = (size_t)B_ * S_ * HID;
    const size_t K_OFF = 2 * Q_OFF;
    const float* cosT = out;                  // [2048*64]
    const float* sinT = out + 131072;

    int z = blockIdx.z;
    const unsigned short* W = Wt + (size_t)z * HID * HID;
    const float* bias = (z == 0) ? bq : ((z == 1) ? bk : bv);

    int n0 = blockIdx.x * BN, m0 = blockIdx.y * BM;
    int tid = threadIdx.x;
    int wave = tid >> 6, lane = tid & 63;
    int quad = lane >> 4, l15 = lane & 15;
    int wm = (wave >> 1) * 64;   // wave's 64-row slab within tile
    int wn = (wave & 1) * 64;

    const unsigned short* Ag = Xb + (size_t)m0 * HID;
    const unsigned short* Bg = W  + (size_t)n0 * HID;

    // per-thread staging slots: e = i*256+tid -> row=e>>2, kc=(e&3)*8
    int e0 = tid, e1 = 256 + tid;
    int r0 = e0 >> 2, c0 = (e0 & 3) * 8;
    int r1 = e1 >> 2, c1 = (e1 & 3) * 8;

    f32x4 acc[4][4] = {};

    for (int k0 = 0; k0 < HID; k0 += BKQ) {
        async16(Ag + (size_t)r0 * HID + k0 + c0, &As[e0 * 8]);
        async16(Ag + (size_t)r1 * HID + k0 + c1, &As[e1 * 8]);
        async16(Bg + (size_t)r0 * HID + k0 + c0, &Bs[e0 * 8]);
        async16(Bg + (size_t)r1 * HID + k0 + c1, &Bs[e1 * 8]);
        __syncthreads();

        bf16x8 af[4], bf[4];
        for (int t = 0; t < 4; t++)
            af[t] = *(const bf16x8*)&As[(wm + t * 16 + l15) * BKQ + quad * 8];
        for (int t = 0; t < 4; t++)
            bf[t] = *(const bf16x8*)&Bs[(wn + t * 16 + l15) * BKQ + quad * 8];
        for (int rt = 0; rt < 4; rt++)
            for (int ct = 0; ct < 4; ct++)
                acc[rt][ct] = __builtin_amdgcn_mfma_f32_16x16x32_bf16(
                    af[rt], bf[ct], acc[rt][ct], 0, 0, 0);
        __syncthreads();
    }

    // epilogue: C/D layout col = l15, row = quad*4 + r
    for (int ct = 0; ct < 4; ct++) {
        int n = n0 + wn + ct * 16 + l15;
        float bval = bias[n];
        int h = n >> 6, d = n & 63;
        for (int rt = 0; rt < 4; rt++) {
            for (int r = 0; r < 4; r++) {
                int m = m0 + wm + rt * 16 + quad * 4 + r;
                int b = m >> 11, s = m & (S_ - 1);
                float y = acc[rt][ct][r] + bval;
                size_t o = ((size_t)(b * H_ + h) * S_ + s) * D_ + d;
                if (z < 2) {
                    float c  = cosT[s * 64 + d];
                    float sn = sinT[s * 64 + d];
                    float p = __shfl_xor(y, 1);
                    float yr = ((d & 1) == 0) ? (y * c - p * sn) : (y * c + p * sn);
                    if (z == 0) { out[Q_OFF + o] = yr; Qb[o] = f2bf(yr); }
                    else        { out[K_OFF + o] = yr; Kb[o] = f2bf(yr); }
                } else {
                    Vb[o] = f2bf(y);
                }
            }
        }
    }
}

// ---------------------------------------------------------------------------
// Kernel 3b: transpose V: Vb[bh][s][d] -> Vt[bh][d][s]
// ---------------------------------------------------------------------------
__global__ __launch_bounds__(256) void transpose_v_kernel(
    const unsigned short* __restrict__ Vb, unsigned short* __restrict__ Vt)
{
    __shared__ unsigned short t[64][72];
    int bh = blockIdx.y;
    int s0 = blockIdx.x * 64;
    const unsigned short* src = Vb + ((size_t)bh * S_ + s0) * D_;
    unsigned short* dst = Vt + (size_t)bh * D_ * S_;
    int tid = threadIdx.x;
    for (int i = 0; i < 2; i++) {
        int e = i * 256 + tid;
        int row = e >> 3, c = (e & 7) * 8;
        u16x8 v = *(const u16x8*)(src + (size_t)row * D_ + c);
        for (int j = 0; j < 8; j++) t[row][c + j] = v[j];
    }
    __syncthreads();
    for (int i = 0; i < 2; i++) {
        int e = i * 256 + tid;
        int d = e >> 3, sc = (e & 7) * 8;
        u16x8 v;
        for (int j = 0; j < 8; j++) v[j] = t[sc + j][d];
        *(u16x8*)(dst + (size_t)d * S_ + s0 + sc) = v;
    }
}

// ---------------------------------------------------------------------------
// Kernel 4: flash attention, barrier-free KV loop.
// S^T = K.Q^T (C: col=q=l15, row=kv) -> in-register softmax (2 shfls) ->
// P^T via per-wave-private LDS -> O^T = V^T.P^T with V^T direct from global.
// grid (H fast -> XCD = h%8 keeps a head's K/V L2-resident, S/64, B).
// ---------------------------------------------------------------------------
#define PPAD 72

__global__ __launch_bounds__(256, 2) void attn_kernel(
    const unsigned short* __restrict__ Qb, const unsigned short* __restrict__ Kb,
    const unsigned short* __restrict__ Vt, const float* __restrict__ mask,
    float* __restrict__ out)
{
    // per-wave private scratch: P^T (16x72 u16 = 2304B) and epilogue O (16x68 f32)
    __shared__ float o_smem[4][16][68];

    int h  = blockIdx.x;
    int qt = blockIdx.y;
    int b  = blockIdx.z;
    int tid = threadIdx.x;
    int wave = tid >> 6, lane = tid & 63;
    int quad = lane >> 4, l15 = lane & 15;
    int q0 = qt * 64 + wave * 16;             // this wave's q rows

    unsigned short* p_lds = (unsigned short*)&o_smem[wave][0][0]; // [16][PPAD]

    size_t bh = (size_t)(b * H_ + h);
    const unsigned short* Qp = Qb + bh * S_ * D_;
    const unsigned short* Kp = Kb + bh * S_ * D_;
    const unsigned short* Vp = Vt + bh * D_ * S_;
    const float* mp = mask + (size_t)b * S_;

    // Q B-fragments (n=q=l15, k=d=hf*32+quad*8+j), registers for whole loop
    bf16x8 qb[2];
    for (int hf = 0; hf < 2; hf++)
        qb[hf] = *(const bf16x8*)(Qp + (size_t)(q0 + l15) * D_ + hf * 32 + quad * 8);

    f32x4 o[4] = {};          // O^T tiles: m = d = ct*16+.., n = q = l15
    float m2 = -1e30f, l = 0.0f;
    const float C2    = 0.03125f * 1.44269504f;   // (1/sqrt(1024)) * log2(e)
    const float LOG2E = 1.44269504f;

    for (int kv0 = 0; kv0 < S_; kv0 += 64) {
        // S^T: A = K rows (m=kv), B = Q (n=q)
        f32x4 sa[4] = {};
        for (int mt = 0; mt < 4; mt++) {
            for (int hf = 0; hf < 2; hf++) {
                bf16x8 kf = *(const bf16x8*)(Kp + (size_t)(kv0 + mt * 16 + l15) * D_ + hf * 32 + quad * 8);
                sa[mt] = __builtin_amdgcn_mfma_f32_16x16x32_bf16(kf, qb[hf], sa[mt], 0, 0, 0);
            }
        }
        // base-2 scaled scores + mask; row max over kv (in-register + 2 shfls)
        float s2[4][4];
        float rmax = -1e30f;
        for (int mt = 0; mt < 4; mt++)
            for (int r = 0; r < 4; r++) {
                float mk = mp[kv0 + mt * 16 + quad * 4 + r];
                s2[mt][r] = sa[mt][r] * C2 + mk * LOG2E;
                rmax = fmaxf(rmax, s2[mt][r]);
            }
        rmax = fmaxf(rmax, __shfl_xor(rmax, 16));
        rmax = fmaxf(rmax, __shfl_xor(rmax, 32));
        float m2n = fmaxf(m2, rmax);
        float alpha = exp2f(m2 - m2n);
        m2 = m2n;

        float psum = 0.0f;
        for (int mt = 0; mt < 4; mt++) {
            u16x4 pv;
            for (int r = 0; r < 4; r++) {
                float p = exp2f(s2[mt][r] - m2n);
                psum += p;
                pv[r] = f2bf_trunc(p);
            }
            // P^T[q=l15][kv = mt*16+quad*4 + r]
            *(u16x4*)&p_lds[l15 * PPAD + mt * 16 + quad * 4] = pv;
        }
        psum += __shfl_xor(psum, 16);
        psum += __shfl_xor(psum, 32);
        l = l * alpha + psum;
        for (int ct = 0; ct < 4; ct++)
            for (int r = 0; r < 4; r++) o[ct][r] *= alpha;

        // PV: B = P^T (n=q=l15, k=kv), A = V^T rows (m=d)   [intra-wave LDS dep]
        bf16x8 pb[2];
        for (int hf = 0; hf < 2; hf++)
            pb[hf] = *(const bf16x8*)&p_lds[l15 * PPAD + hf * 32 + quad * 8];
        for (int ct = 0; ct < 4; ct++) {
            for (int hf = 0; hf < 2; hf++) {
                bf16x8 vf = *(const bf16x8*)(Vp + (size_t)(ct * 16 + l15) * S_ + kv0 + hf * 32 + quad * 8);
                o[ct] = __builtin_amdgcn_mfma_f32_16x16x32_bf16(vf, pb[hf], o[ct], 0, 0, 0);
            }
        }
    }

    // epilogue: normalize, transpose via LDS, coalesced store
    float inv = 1.0f / l;
    for (int ct = 0; ct < 4; ct++) {
        float4 vv;
        vv.x = o[ct][0] * inv; vv.y = o[ct][1] * inv;
        vv.z = o[ct][2] * inv; vv.w = o[ct][3] * inv;
        *(float4*)&o_smem[wave][l15][ct * 16 + quad * 4] = vv;
    }
    __builtin_amdgcn_wave_barrier();
    {
        int qq = lane >> 2, d0 = (lane & 3) * 16;
        int s_abs = qt * 64 + wave * 16 + qq;
        float* dst = out + ((size_t)b * S_ + s_abs) * (H_ * D_) + h * D_ + d0;
        for (int j = 0; j < 4; j++) {
            float4 vj = *(float4*)&o_smem[wave][qq][d0 + j * 4];
            *(float4*)(dst + j * 4) = vj;
        }
    }
}

// ---------------------------------------------------------------------------
extern "C" void kernel_launch(void* const* d_in, const int* in_sizes, int n_in,
                              void* d_out, int out_size, void* d_ws, size_t ws_size,
                              hipStream_t stream)
{
    const float* X    = (const float*)d_in[0];
    const float* Wq   = (const float*)d_in[1];
    const float* bq   = (const float*)d_in[2];
    const float* Wk   = (const float*)d_in[3];
    const float* bk   = (const float*)d_in[4];
    const float* Wv   = (const float*)d_in[5];
    const float* bv   = (const float*)d_in[6];
    const float* mask = (const float*)d_in[7];

    // workspace layout (bytes)
    char* ws = (char*)d_ws;
    unsigned short* Xb = (unsigned short*)(ws);                      // 16 MB (reused as Vt)
    unsigned short* Wt = (unsigned short*)(ws + 16777216);           //  6 MB
    unsigned short* Qb = (unsigned short*)(ws + 23068672);           // 16 MB
    unsigned short* Kb = (unsigned short*)(ws + 39845888);           // 16 MB
    unsigned short* Vb = (unsigned short*)(ws + 56623104);           // 16 MB
    unsigned short* Vt = Xb;   // Xb dead after qkv_gemm; reuse for V^T

    // RoPE tables live in d_out's ctx region (fully overwritten by attn later)
    rope_table_kernel<<<dim3(131072 / 256), 256, 0, stream>>>((float*)d_out);
    cast_x_kernel<<<dim3(M_ * HID / 4 / 256), 256, 0, stream>>>(X, Xb);
    cast_wt_kernel<<<dim3(16, 16, 3), 256, 0, stream>>>(Wq, Wk, Wv, Wt);
    qkv_gemm_kernel<<<dim3(HID / BN, M_ / BM, 3), 256, 0, stream>>>(
        Xb, Wt, bq, bk, bv, (float*)d_out, Qb, Kb, Vb);
    transpose_v_kernel<<<dim3(S_ / 64, B_ * H_), 256, 0, stream>>>(Vb, Vt);
    attn_kernel<<<dim3(H_, S_ / 64, B_), 256, 0, stream>>>(
        Qb, Kb, Vt, mask, (float*)d_out);
}

// Round 4
// 1538.933 us; speedup vs baseline: 1.1106x; 1.1106x over previous
//
#include <hip/hip_runtime.h>

// ---------------------------------------------------------------------------
// MultiHeadsAttention: X[4,2048,1024] -> ctx[4,2048,1024], q[4,16,2048,64],
// k[4,16,2048,64] (q,k post-RoPE). fp32 in/out, bf16 MFMA internally.
// Round 4: inline-asm MFMA with "+a" accumulators to FORCE AGPR allocation
// (rounds 2/3 spilled acc[4][4] to scratch: 3.2 GB HBM writes, MfmaUtil 2%).
// ---------------------------------------------------------------------------

#define B_  4
#define S_  2048
#define H_  16
#define D_  64
#define HID 1024
#define M_  (B_ * S_)          // 8192

typedef __attribute__((ext_vector_type(8))) short    bf16x8;
typedef __attribute__((ext_vector_type(4))) float    f32x4;
typedef __attribute__((ext_vector_type(4))) unsigned short u16x4;
typedef __attribute__((ext_vector_type(8))) unsigned short u16x8;

__device__ __forceinline__ unsigned short f2bf(float f) {
    union { float f; unsigned u; } v; v.f = f;
    unsigned r = v.u + 0x7fffu + ((v.u >> 16) & 1u);
    return (unsigned short)(r >> 16);
}
__device__ __forceinline__ unsigned short f2bf_trunc(float f) {
    union { float f; unsigned u; } v; v.f = f;
    return (unsigned short)(v.u >> 16);
}

// MFMA with accumulator pinned to AGPR class (D=C="+a").
__device__ __forceinline__ void mfma_a(f32x4& c, bf16x8 a, bf16x8 b) {
    asm("v_mfma_f32_16x16x32_bf16 %0, %1, %2, %0"
        : "+a"(c) : "v"(a), "v"(b));
}

__device__ __forceinline__ void async16(const unsigned short* g, unsigned short* l) {
    __builtin_amdgcn_global_load_lds(
        (const __attribute__((address_space(1))) void*)g,
        (__attribute__((address_space(3))) void*)l, 16, 0, 0);
}

// ---------------------------------------------------------------------------
// Kernel 0: RoPE tables -> d_out ctx region (overwritten later by attn).
// ---------------------------------------------------------------------------
__global__ __launch_bounds__(256) void rope_table_kernel(float* __restrict__ tab)
{
    int i = blockIdx.x * 256 + threadIdx.x;     // 0 .. 131071
    int s = i >> 6, d = i & 63;
    const float NEG_LN1E4_32 = -0.28782313662425576f;  // -ln(10000)/32
    float freq = __expf(NEG_LN1E4_32 * (float)(d >> 1));
    float ang = (float)s * freq;
    tab[i]          = cosf(ang);
    tab[131072 + i] = sinf(ang);
}

// ---------------------------------------------------------------------------
// Kernel 1: cast X fp32 -> bf16
// ---------------------------------------------------------------------------
__global__ __launch_bounds__(256) void cast_x_kernel(
    const float* __restrict__ X, unsigned short* __restrict__ Xb)
{
    int i = (blockIdx.x * 256 + threadIdx.x) * 4;
    float4 v = *(const float4*)(X + i);
    u16x4 o;
    o[0] = f2bf(v.x); o[1] = f2bf(v.y); o[2] = f2bf(v.z); o[3] = f2bf(v.w);
    *(u16x4*)(Xb + i) = o;
}

// ---------------------------------------------------------------------------
// Kernel 2: transpose+cast W[k][n] fp32 -> Wt[n][k] bf16  (z selects q/k/v)
// ---------------------------------------------------------------------------
__global__ __launch_bounds__(256) void cast_wt_kernel(
    const float* __restrict__ Wq, const float* __restrict__ Wk,
    const float* __restrict__ Wv, unsigned short* __restrict__ Wt)
{
    __shared__ float tile[64][65];
    int z = blockIdx.z;
    const float* W = (z == 0) ? Wq : ((z == 1) ? Wk : Wv);
    unsigned short* out = Wt + (size_t)z * HID * HID;
    int n0 = blockIdx.x * 64, k0 = blockIdx.y * 64;
    int tx = threadIdx.x & 63, ty0 = threadIdx.x >> 6;
    for (int i = 0; i < 16; i++) {
        int ty = ty0 * 16 + i;
        tile[ty][tx] = W[(size_t)(k0 + ty) * HID + n0 + tx];
    }
    __syncthreads();
    for (int i = 0; i < 16; i++) {
        int ty = ty0 * 16 + i;
        out[(size_t)(n0 + ty) * HID + k0 + tx] = f2bf(tile[tx][ty]);
    }
}

// ---------------------------------------------------------------------------
// Kernel 3: QKV GEMM, 128x128 tile, BK=32, global_load_lds staging,
// 4 waves each 64x64 (4x4 frags of 16x16x32 MFMA, AGPR accumulators).
// Epilogue fuses bias + table-RoPE.
// ---------------------------------------------------------------------------
#define BM 128
#define BN 128
#define BKQ 32

__global__ __launch_bounds__(256)
__attribute__((amdgpu_waves_per_eu(2, 4)))
void qkv_gemm_kernel(
    const unsigned short* __restrict__ Xb, const unsigned short* __restrict__ Wt,
    const float* __restrict__ bq, const float* __restrict__ bk,
    const float* __restrict__ bv,
    const float* __restrict__ cosT, const float* __restrict__ sinT,
    float* out,
    unsigned short* __restrict__ Qb, unsigned short* __restrict__ Kb,
    unsigned short* __restrict__ Vb)
{
    __shared__ unsigned short As[BM * BKQ];   // row-major [128][32], unpadded
    __shared__ unsigned short Bs[BN * BKQ];   // (global_load_lds layout rule)

    const size_t Q_OFF = (size_t)B_ * S_ * HID;
    const size_t K_OFF = 2 * Q_OFF;

    int z = blockIdx.z;
    const unsigned short* W = Wt + (size_t)z * HID * HID;
    const float* bias = (z == 0) ? bq : ((z == 1) ? bk : bv);

    int n0 = blockIdx.x * BN, m0 = blockIdx.y * BM;
    int tid = threadIdx.x;
    int wave = tid >> 6, lane = tid & 63;
    int quad = lane >> 4, l15 = lane & 15;
    int wm = (wave >> 1) * 64;
    int wn = (wave & 1) * 64;

    const unsigned short* Ag = Xb + (size_t)m0 * HID;
    const unsigned short* Bg = W  + (size_t)n0 * HID;

    int e0 = tid, e1 = 256 + tid;
    int r0 = e0 >> 2, c0 = (e0 & 3) * 8;
    int r1 = e1 >> 2, c1 = (e1 & 3) * 8;

    f32x4 acc[4][4] = {};

    for (int k0 = 0; k0 < HID; k0 += BKQ) {
        async16(Ag + (size_t)r0 * HID + k0 + c0, &As[e0 * 8]);
        async16(Ag + (size_t)r1 * HID + k0 + c1, &As[e1 * 8]);
        async16(Bg + (size_t)r0 * HID + k0 + c0, &Bs[e0 * 8]);
        async16(Bg + (size_t)r1 * HID + k0 + c1, &Bs[e1 * 8]);
        __syncthreads();

        bf16x8 af[4], bf[4];
        for (int t = 0; t < 4; t++)
            af[t] = *(const bf16x8*)&As[(wm + t * 16 + l15) * BKQ + quad * 8];
        for (int t = 0; t < 4; t++)
            bf[t] = *(const bf16x8*)&Bs[(wn + t * 16 + l15) * BKQ + quad * 8];
        for (int rt = 0; rt < 4; rt++)
            for (int ct = 0; ct < 4; ct++)
                mfma_a(acc[rt][ct], af[rt], bf[ct]);
        __syncthreads();
    }

    asm volatile("s_nop 7\ns_nop 7\ns_nop 7" ::: );   // MFMA->AGPR-read guard

    // epilogue: C/D layout col = l15, row = quad*4 + r
    for (int ct = 0; ct < 4; ct++) {
        int n = n0 + wn + ct * 16 + l15;
        float bval = bias[n];
        int h = n >> 6, d = n & 63;
        for (int rt = 0; rt < 4; rt++) {
            for (int r = 0; r < 4; r++) {
                int m = m0 + wm + rt * 16 + quad * 4 + r;
                int b = m >> 11, s = m & (S_ - 1);
                float y = acc[rt][ct][r] + bval;
                size_t o = ((size_t)(b * H_ + h) * S_ + s) * D_ + d;
                if (z < 2) {
                    float c  = cosT[s * 64 + d];
                    float sn = sinT[s * 64 + d];
                    float p = __shfl_xor(y, 1);
                    float yr = ((d & 1) == 0) ? (y * c - p * sn) : (y * c + p * sn);
                    if (z == 0) { out[Q_OFF + o] = yr; Qb[o] = f2bf(yr); }
                    else        { out[K_OFF + o] = yr; Kb[o] = f2bf(yr); }
                } else {
                    Vb[o] = f2bf(y);
                }
            }
        }
    }
}

// ---------------------------------------------------------------------------
// Kernel 3b: transpose V: Vb[bh][s][d] -> Vt[bh][d][s]
// ---------------------------------------------------------------------------
__global__ __launch_bounds__(256) void transpose_v_kernel(
    const unsigned short* __restrict__ Vb, unsigned short* __restrict__ Vt)
{
    __shared__ unsigned short t[64][72];
    int bh = blockIdx.y;
    int s0 = blockIdx.x * 64;
    const unsigned short* src = Vb + ((size_t)bh * S_ + s0) * D_;
    unsigned short* dst = Vt + (size_t)bh * D_ * S_;
    int tid = threadIdx.x;
    for (int i = 0; i < 2; i++) {
        int e = i * 256 + tid;
        int row = e >> 3, c = (e & 7) * 8;
        u16x8 v = *(const u16x8*)(src + (size_t)row * D_ + c);
        for (int j = 0; j < 8; j++) t[row][c + j] = v[j];
    }
    __syncthreads();
    for (int i = 0; i < 2; i++) {
        int e = i * 256 + tid;
        int d = e >> 3, sc = (e & 7) * 8;
        u16x8 v;
        for (int j = 0; j < 8; j++) v[j] = t[sc + j][d];
        *(u16x8*)(dst + (size_t)d * S_ + s0 + sc) = v;
    }
}

// ---------------------------------------------------------------------------
// Kernel 4: flash attention, barrier-free KV loop, AGPR O-accumulator.
// S^T = K.Q^T -> in-register softmax (2 shfls) -> P^T via per-wave-private
// LDS -> O^T = V^T.P^T with V^T direct from global.
// ---------------------------------------------------------------------------
#define PPAD 72

__global__ __launch_bounds__(256)
__attribute__((amdgpu_waves_per_eu(2, 4)))
void attn_kernel(
    const unsigned short* __restrict__ Qb, const unsigned short* __restrict__ Kb,
    const unsigned short* __restrict__ Vt, const float* __restrict__ mask,
    float* __restrict__ out)
{
    __shared__ float o_smem[4][16][68];

    int h  = blockIdx.x;
    int qt = blockIdx.y;
    int b  = blockIdx.z;
    int tid = threadIdx.x;
    int wave = tid >> 6, lane = tid & 63;
    int quad = lane >> 4, l15 = lane & 15;
    int q0 = qt * 64 + wave * 16;

    unsigned short* p_lds = (unsigned short*)&o_smem[wave][0][0]; // [16][PPAD]

    size_t bh = (size_t)(b * H_ + h);
    const unsigned short* Qp = Qb + bh * S_ * D_;
    const unsigned short* Kp = Kb + bh * S_ * D_;
    const unsigned short* Vp = Vt + bh * D_ * S_;
    const float* mp = mask + (size_t)b * S_;

    bf16x8 qb[2];
    for (int hf = 0; hf < 2; hf++)
        qb[hf] = *(const bf16x8*)(Qp + (size_t)(q0 + l15) * D_ + hf * 32 + quad * 8);

    f32x4 o[4] = {};          // AGPR via mfma_a
    float m2 = -1e30f, l = 0.0f;
    const float C2    = 0.03125f * 1.44269504f;   // (1/sqrt(1024)) * log2(e)
    const float LOG2E = 1.44269504f;

    for (int kv0 = 0; kv0 < S_; kv0 += 64) {
        // S^T: A = K rows (m=kv), B = Q (n=q)
        f32x4 sa[4] = {};
        for (int mt = 0; mt < 4; mt++) {
            for (int hf = 0; hf < 2; hf++) {
                bf16x8 kf = *(const bf16x8*)(Kp + (size_t)(kv0 + mt * 16 + l15) * D_ + hf * 32 + quad * 8);
                sa[mt] = __builtin_amdgcn_mfma_f32_16x16x32_bf16(kf, qb[hf], sa[mt], 0, 0, 0);
            }
        }
        // base-2 scaled scores + mask; row max (in-register + 2 shfls)
        float s2[4][4];
        float rmax = -1e30f;
        for (int mt = 0; mt < 4; mt++)
            for (int r = 0; r < 4; r++) {
                float mk = mp[kv0 + mt * 16 + quad * 4 + r];
                s2[mt][r] = sa[mt][r] * C2 + mk * LOG2E;
                rmax = fmaxf(rmax, s2[mt][r]);
            }
        rmax = fmaxf(rmax, __shfl_xor(rmax, 16));
        rmax = fmaxf(rmax, __shfl_xor(rmax, 32));
        float m2n = fmaxf(m2, rmax);
        float alpha = exp2f(m2 - m2n);
        m2 = m2n;

        float psum = 0.0f;
        for (int mt = 0; mt < 4; mt++) {
            u16x4 pv;
            for (int r = 0; r < 4; r++) {
                float p = exp2f(s2[mt][r] - m2n);
                psum += p;
                pv[r] = f2bf_trunc(p);
            }
            *(u16x4*)&p_lds[l15 * PPAD + mt * 16 + quad * 4] = pv;
        }
        psum += __shfl_xor(psum, 16);
        psum += __shfl_xor(psum, 32);
        l = l * alpha + psum;
        for (int ct = 0; ct < 4; ct++)
            for (int r = 0; r < 4; r++) o[ct][r] *= alpha;

        // PV: B = P^T (n=q=l15, k=kv), A = V^T rows (m=d)
        bf16x8 pb[2];
        for (int hf = 0; hf < 2; hf++)
            pb[hf] = *(const bf16x8*)&p_lds[l15 * PPAD + hf * 32 + quad * 8];
        for (int ct = 0; ct < 4; ct++) {
            for (int hf = 0; hf < 2; hf++) {
                bf16x8 vf = *(const bf16x8*)(Vp + (size_t)(ct * 16 + l15) * S_ + kv0 + hf * 32 + quad * 8);
                mfma_a(o[ct], vf, pb[hf]);
            }
        }
    }

    asm volatile("s_nop 7\ns_nop 7\ns_nop 7" ::: );   // MFMA->AGPR-read guard

    // epilogue: normalize, transpose via LDS, coalesced store
    float inv = 1.0f / l;
    for (int ct = 0; ct < 4; ct++) {
        float4 vv;
        vv.x = o[ct][0] * inv; vv.y = o[ct][1] * inv;
        vv.z = o[ct][2] * inv; vv.w = o[ct][3] * inv;
        *(float4*)&o_smem[wave][l15][ct * 16 + quad * 4] = vv;
    }
    __builtin_amdgcn_wave_barrier();
    {
        int qq = lane >> 2, d0 = (lane & 3) * 16;
        int s_abs = qt * 64 + wave * 16 + qq;
        float* dst = out + ((size_t)b * S_ + s_abs) * (H_ * D_) + h * D_ + d0;
        for (int j = 0; j < 4; j++) {
            float4 vj = *(float4*)&o_smem[wave][qq][d0 + j * 4];
            *(float4*)(dst + j * 4) = vj;
        }
    }
}

// ---------------------------------------------------------------------------
extern "C" void kernel_launch(void* const* d_in, const int* in_sizes, int n_in,
                              void* d_out, int out_size, void* d_ws, size_t ws_size,
                              hipStream_t stream)
{
    const float* X    = (const float*)d_in[0];
    const float* Wq   = (const float*)d_in[1];
    const float* bq   = (const float*)d_in[2];
    const float* Wk   = (const float*)d_in[3];
    const float* bk   = (const float*)d_in[4];
    const float* Wv   = (const float*)d_in[5];
    const float* bv   = (const float*)d_in[6];
    const float* mask = (const float*)d_in[7];

    char* ws = (char*)d_ws;
    unsigned short* Xb = (unsigned short*)(ws);                      // 16 MB (reused as Vt)
    unsigned short* Wt = (unsigned short*)(ws + 16777216);           //  6 MB
    unsigned short* Qb = (unsigned short*)(ws + 23068672);           // 16 MB
    unsigned short* Kb = (unsigned short*)(ws + 39845888);           // 16 MB
    unsigned short* Vb = (unsigned short*)(ws + 56623104);           // 16 MB
    unsigned short* Vt = Xb;   // Xb dead after qkv_gemm; reuse for V^T

    float* tab = (float*)d_out;   // RoPE tables in ctx region (overwritten by attn)

    rope_table_kernel<<<dim3(131072 / 256), 256, 0, stream>>>(tab);
    cast_x_kernel<<<dim3(M_ * HID / 4 / 256), 256, 0, stream>>>(X, Xb);
    cast_wt_kernel<<<dim3(16, 16, 3), 256, 0, stream>>>(Wq, Wk, Wv, Wt);
    qkv_gemm_kernel<<<dim3(HID / BN, M_ / BM, 3), 256, 0, stream>>>(
        Xb, Wt, bq, bk, bv, tab, tab + 131072, (float*)d_out, Qb, Kb, Vb);
    transpose_v_kernel<<<dim3(S_ / 64, B_ * H_), 256, 0, stream>>>(Vb, Vt);
    attn_kernel<<<dim3(H_, S_ / 64, B_), 256, 0, stream>>>(
        Qb, Kb, Vt, mask, (float*)d_out);
}

// Round 5
// 737.022 us; speedup vs baseline: 2.3190x; 2.0880x over previous
//
#include <hip/hip_runtime.h>

// ---------------------------------------------------------------------------
// MultiHeadsAttention: X[4,2048,1024] -> ctx[4,2048,1024], q[4,16,2048,64],
// k[4,16,2048,64] (q,k post-RoPE). fp32 in/out, bf16 MFMA internally.
// Round 5: r2-r4 regression root-caused: WITHOUT #pragma unroll the 4x4 acc
// array fails SROA and lives in scratch (3.1 GB HBM writes = 256B/thr/iter,
// VGPR_Count 52 under a 256-reg budget proves it was never reg pressure).
// Fix: force full unroll of every acc/frag-indexing loop; plain builtin MFMA.
// ---------------------------------------------------------------------------

#define B_  4
#define S_  2048
#define H_  16
#define D_  64
#define HID 1024
#define M_  (B_ * S_)          // 8192

typedef __attribute__((ext_vector_type(8))) short    bf16x8;
typedef __attribute__((ext_vector_type(4))) float    f32x4;
typedef __attribute__((ext_vector_type(4))) unsigned short u16x4;
typedef __attribute__((ext_vector_type(8))) unsigned short u16x8;

__device__ __forceinline__ unsigned short f2bf(float f) {
    union { float f; unsigned u; } v; v.f = f;
    unsigned r = v.u + 0x7fffu + ((v.u >> 16) & 1u);
    return (unsigned short)(r >> 16);
}
__device__ __forceinline__ unsigned short f2bf_trunc(float f) {
    union { float f; unsigned u; } v; v.f = f;
    return (unsigned short)(v.u >> 16);
}

__device__ __forceinline__ void async16(const unsigned short* g, unsigned short* l) {
    __builtin_amdgcn_global_load_lds(
        (const __attribute__((address_space(1))) void*)g,
        (__attribute__((address_space(3))) void*)l, 16, 0, 0);
}

// ---------------------------------------------------------------------------
// Kernel 0: RoPE tables -> d_out ctx region (overwritten later by attn).
// ---------------------------------------------------------------------------
__global__ __launch_bounds__(256) void rope_table_kernel(float* __restrict__ tab)
{
    int i = blockIdx.x * 256 + threadIdx.x;     // 0 .. 131071
    int s = i >> 6, d = i & 63;
    const float NEG_LN1E4_32 = -0.28782313662425576f;  // -ln(10000)/32
    float freq = __expf(NEG_LN1E4_32 * (float)(d >> 1));
    float ang = (float)s * freq;
    tab[i]          = cosf(ang);
    tab[131072 + i] = sinf(ang);
}

// ---------------------------------------------------------------------------
// Kernel 1: cast X fp32 -> bf16
// ---------------------------------------------------------------------------
__global__ __launch_bounds__(256) void cast_x_kernel(
    const float* __restrict__ X, unsigned short* __restrict__ Xb)
{
    int i = (blockIdx.x * 256 + threadIdx.x) * 4;
    float4 v = *(const float4*)(X + i);
    u16x4 o;
    o[0] = f2bf(v.x); o[1] = f2bf(v.y); o[2] = f2bf(v.z); o[3] = f2bf(v.w);
    *(u16x4*)(Xb + i) = o;
}

// ---------------------------------------------------------------------------
// Kernel 2: transpose+cast W[k][n] fp32 -> Wt[n][k] bf16  (z selects q/k/v)
// ---------------------------------------------------------------------------
__global__ __launch_bounds__(256) void cast_wt_kernel(
    const float* __restrict__ Wq, const float* __restrict__ Wk,
    const float* __restrict__ Wv, unsigned short* __restrict__ Wt)
{
    __shared__ float tile[64][65];
    int z = blockIdx.z;
    const float* W = (z == 0) ? Wq : ((z == 1) ? Wk : Wv);
    unsigned short* out = Wt + (size_t)z * HID * HID;
    int n0 = blockIdx.x * 64, k0 = blockIdx.y * 64;
    int tx = threadIdx.x & 63, ty0 = threadIdx.x >> 6;
#pragma unroll
    for (int i = 0; i < 16; i++) {
        int ty = ty0 * 16 + i;
        tile[ty][tx] = W[(size_t)(k0 + ty) * HID + n0 + tx];
    }
    __syncthreads();
#pragma unroll
    for (int i = 0; i < 16; i++) {
        int ty = ty0 * 16 + i;
        out[(size_t)(n0 + ty) * HID + k0 + tx] = f2bf(tile[tx][ty]);
    }
}

// ---------------------------------------------------------------------------
// Kernel 3: QKV GEMM, 128x128 tile, BK=32, global_load_lds staging,
// 4 waves each 64x64 (4x4 frags of 16x16x32 MFMA). Bias + table-RoPE epilogue.
// ---------------------------------------------------------------------------
#define BM 128
#define BN 128
#define BKQ 32

__global__ __launch_bounds__(256) void qkv_gemm_kernel(
    const unsigned short* __restrict__ Xb, const unsigned short* __restrict__ Wt,
    const float* __restrict__ bq, const float* __restrict__ bk,
    const float* __restrict__ bv,
    const float* __restrict__ cosT, const float* __restrict__ sinT,
    float* out,
    unsigned short* __restrict__ Qb, unsigned short* __restrict__ Kb,
    unsigned short* __restrict__ Vb)
{
    __shared__ unsigned short As[BM * BKQ];   // row-major [128][32], unpadded
    __shared__ unsigned short Bs[BN * BKQ];   // (global_load_lds layout rule)

    const size_t Q_OFF = (size_t)B_ * S_ * HID;
    const size_t K_OFF = 2 * Q_OFF;

    int z = blockIdx.z;
    const unsigned short* W = Wt + (size_t)z * HID * HID;
    const float* bias = (z == 0) ? bq : ((z == 1) ? bk : bv);

    int n0 = blockIdx.x * BN, m0 = blockIdx.y * BM;
    int tid = threadIdx.x;
    int wave = tid >> 6, lane = tid & 63;
    int quad = lane >> 4, l15 = lane & 15;
    int wm = (wave >> 1) * 64;
    int wn = (wave & 1) * 64;

    const unsigned short* Ag = Xb + (size_t)m0 * HID;
    const unsigned short* Bg = W  + (size_t)n0 * HID;

    int e0 = tid, e1 = 256 + tid;
    int r0 = e0 >> 2, c0 = (e0 & 3) * 8;
    int r1 = e1 >> 2, c1 = (e1 & 3) * 8;

    f32x4 acc[4][4] = {};

    for (int k0 = 0; k0 < HID; k0 += BKQ) {
        async16(Ag + (size_t)r0 * HID + k0 + c0, &As[e0 * 8]);
        async16(Ag + (size_t)r1 * HID + k0 + c1, &As[e1 * 8]);
        async16(Bg + (size_t)r0 * HID + k0 + c0, &Bs[e0 * 8]);
        async16(Bg + (size_t)r1 * HID + k0 + c1, &Bs[e1 * 8]);
        __syncthreads();

        bf16x8 af[4], bf[4];
#pragma unroll
        for (int t = 0; t < 4; t++)
            af[t] = *(const bf16x8*)&As[(wm + t * 16 + l15) * BKQ + quad * 8];
#pragma unroll
        for (int t = 0; t < 4; t++)
            bf[t] = *(const bf16x8*)&Bs[(wn + t * 16 + l15) * BKQ + quad * 8];
#pragma unroll
        for (int rt = 0; rt < 4; rt++)
#pragma unroll
            for (int ct = 0; ct < 4; ct++)
                acc[rt][ct] = __builtin_amdgcn_mfma_f32_16x16x32_bf16(
                    af[rt], bf[ct], acc[rt][ct], 0, 0, 0);
        __syncthreads();
    }

    // epilogue: C/D layout col = l15, row = quad*4 + r
#pragma unroll
    for (int ct = 0; ct < 4; ct++) {
        int n = n0 + wn + ct * 16 + l15;
        float bval = bias[n];
        int h = n >> 6, d = n & 63;
#pragma unroll
        for (int rt = 0; rt < 4; rt++) {
#pragma unroll
            for (int r = 0; r < 4; r++) {
                int m = m0 + wm + rt * 16 + quad * 4 + r;
                int b = m >> 11, s = m & (S_ - 1);
                float y = acc[rt][ct][r] + bval;
                size_t o = ((size_t)(b * H_ + h) * S_ + s) * D_ + d;
                if (z < 2) {
                    float c  = cosT[s * 64 + d];
                    float sn = sinT[s * 64 + d];
                    float p = __shfl_xor(y, 1);
                    float yr = ((d & 1) == 0) ? (y * c - p * sn) : (y * c + p * sn);
                    if (z == 0) { out[Q_OFF + o] = yr; Qb[o] = f2bf(yr); }
                    else        { out[K_OFF + o] = yr; Kb[o] = f2bf(yr); }
                } else {
                    Vb[o] = f2bf(y);
                }
            }
        }
    }
}

// ---------------------------------------------------------------------------
// Kernel 3b: transpose V: Vb[bh][s][d] -> Vt[bh][d][s]
// ---------------------------------------------------------------------------
__global__ __launch_bounds__(256) void transpose_v_kernel(
    const unsigned short* __restrict__ Vb, unsigned short* __restrict__ Vt)
{
    __shared__ unsigned short t[64][72];
    int bh = blockIdx.y;
    int s0 = blockIdx.x * 64;
    const unsigned short* src = Vb + ((size_t)bh * S_ + s0) * D_;
    unsigned short* dst = Vt + (size_t)bh * D_ * S_;
    int tid = threadIdx.x;
#pragma unroll
    for (int i = 0; i < 2; i++) {
        int e = i * 256 + tid;
        int row = e >> 3, c = (e & 7) * 8;
        u16x8 v = *(const u16x8*)(src + (size_t)row * D_ + c);
#pragma unroll
        for (int j = 0; j < 8; j++) t[row][c + j] = v[j];
    }
    __syncthreads();
#pragma unroll
    for (int i = 0; i < 2; i++) {
        int e = i * 256 + tid;
        int d = e >> 3, sc = (e & 7) * 8;
        u16x8 v;
#pragma unroll
        for (int j = 0; j < 8; j++) v[j] = t[sc + j][d];
        *(u16x8*)(dst + (size_t)d * S_ + s0 + sc) = v;
    }
}

// ---------------------------------------------------------------------------
// Kernel 4: flash attention, barrier-free KV loop.
// S^T = K.Q^T -> in-register softmax (2 shfls) -> P^T via per-wave-private
// LDS -> O^T = V^T.P^T with V^T direct from global.
// ---------------------------------------------------------------------------
#define PPAD 72

__global__ __launch_bounds__(256) void attn_kernel(
    const unsigned short* __restrict__ Qb, const unsigned short* __restrict__ Kb,
    const unsigned short* __restrict__ Vt, const float* __restrict__ mask,
    float* __restrict__ out)
{
    __shared__ float o_smem[4][16][68];

    int h  = blockIdx.x;
    int qt = blockIdx.y;
    int b  = blockIdx.z;
    int tid = threadIdx.x;
    int wave = tid >> 6, lane = tid & 63;
    int quad = lane >> 4, l15 = lane & 15;
    int q0 = qt * 64 + wave * 16;

    unsigned short* p_lds = (unsigned short*)&o_smem[wave][0][0]; // [16][PPAD]

    size_t bh = (size_t)(b * H_ + h);
    const unsigned short* Qp = Qb + bh * S_ * D_;
    const unsigned short* Kp = Kb + bh * S_ * D_;
    const unsigned short* Vp = Vt + bh * D_ * S_;
    const float* mp = mask + (size_t)b * S_;

    bf16x8 qb[2];
#pragma unroll
    for (int hf = 0; hf < 2; hf++)
        qb[hf] = *(const bf16x8*)(Qp + (size_t)(q0 + l15) * D_ + hf * 32 + quad * 8);

    f32x4 o[4] = {};
    float m2 = -1e30f, l = 0.0f;
    const float C2    = 0.03125f * 1.44269504f;   // (1/sqrt(1024)) * log2(e)
    const float LOG2E = 1.44269504f;

    for (int kv0 = 0; kv0 < S_; kv0 += 64) {
        // S^T: A = K rows (m=kv), B = Q (n=q)
        f32x4 sa[4] = {};
#pragma unroll
        for (int mt = 0; mt < 4; mt++) {
#pragma unroll
            for (int hf = 0; hf < 2; hf++) {
                bf16x8 kf = *(const bf16x8*)(Kp + (size_t)(kv0 + mt * 16 + l15) * D_ + hf * 32 + quad * 8);
                sa[mt] = __builtin_amdgcn_mfma_f32_16x16x32_bf16(kf, qb[hf], sa[mt], 0, 0, 0);
            }
        }
        // base-2 scaled scores + mask; row max (in-register + 2 shfls)
        float s2[4][4];
        float rmax = -1e30f;
#pragma unroll
        for (int mt = 0; mt < 4; mt++)
#pragma unroll
            for (int r = 0; r < 4; r++) {
                float mk = mp[kv0 + mt * 16 + quad * 4 + r];
                s2[mt][r] = sa[mt][r] * C2 + mk * LOG2E;
                rmax = fmaxf(rmax, s2[mt][r]);
            }
        rmax = fmaxf(rmax, __shfl_xor(rmax, 16));
        rmax = fmaxf(rmax, __shfl_xor(rmax, 32));
        float m2n = fmaxf(m2, rmax);
        float alpha = exp2f(m2 - m2n);
        m2 = m2n;

        float psum = 0.0f;
#pragma unroll
        for (int mt = 0; mt < 4; mt++) {
            u16x4 pv;
#pragma unroll
            for (int r = 0; r < 4; r++) {
                float p = exp2f(s2[mt][r] - m2n);
                psum += p;
                pv[r] = f2bf_trunc(p);
            }
            *(u16x4*)&p_lds[l15 * PPAD + mt * 16 + quad * 4] = pv;
        }
        psum += __shfl_xor(psum, 16);
        psum += __shfl_xor(psum, 32);
        l = l * alpha + psum;
#pragma unroll
        for (int ct = 0; ct < 4; ct++)
#pragma unroll
            for (int r = 0; r < 4; r++) o[ct][r] *= alpha;

        // PV: B = P^T (n=q=l15, k=kv), A = V^T rows (m=d)
        bf16x8 pb[2];
#pragma unroll
        for (int hf = 0; hf < 2; hf++)
            pb[hf] = *(const bf16x8*)&p_lds[l15 * PPAD + hf * 32 + quad * 8];
#pragma unroll
        for (int ct = 0; ct < 4; ct++) {
#pragma unroll
            for (int hf = 0; hf < 2; hf++) {
                bf16x8 vf = *(const bf16x8*)(Vp + (size_t)(ct * 16 + l15) * S_ + kv0 + hf * 32 + quad * 8);
                o[ct] = __builtin_amdgcn_mfma_f32_16x16x32_bf16(vf, pb[hf], o[ct], 0, 0, 0);
            }
        }
    }

    // epilogue: normalize, transpose via LDS, coalesced store
    float inv = 1.0f / l;
#pragma unroll
    for (int ct = 0; ct < 4; ct++) {
        float4 vv;
        vv.x = o[ct][0] * inv; vv.y = o[ct][1] * inv;
        vv.z = o[ct][2] * inv; vv.w = o[ct][3] * inv;
        *(float4*)&o_smem[wave][l15][ct * 16 + quad * 4] = vv;
    }
    __builtin_amdgcn_wave_barrier();
    {
        int qq = lane >> 2, d0 = (lane & 3) * 16;
        int s_abs = qt * 64 + wave * 16 + qq;
        float* dst = out + ((size_t)b * S_ + s_abs) * (H_ * D_) + h * D_ + d0;
#pragma unroll
        for (int j = 0; j < 4; j++) {
            float4 vj = *(float4*)&o_smem[wave][qq][d0 + j * 4];
            *(float4*)(dst + j * 4) = vj;
        }
    }
}

// ---------------------------------------------------------------------------
extern "C" void kernel_launch(void* const* d_in, const int* in_sizes, int n_in,
                              void* d_out, int out_size, void* d_ws, size_t ws_size,
                              hipStream_t stream)
{
    const float* X    = (const float*)d_in[0];
    const float* Wq   = (const float*)d_in[1];
    const float* bq   = (const float*)d_in[2];
    const float* Wk   = (const float*)d_in[3];
    const float* bk   = (const float*)d_in[4];
    const float* Wv   = (const float*)d_in[5];
    const float* bv   = (const float*)d_in[6];
    const float* mask = (const float*)d_in[7];

    char* ws = (char*)d_ws;
    unsigned short* Xb = (unsigned short*)(ws);                      // 16 MB (reused as Vt)
    unsigned short* Wt = (unsigned short*)(ws + 16777216);           //  6 MB
    unsigned short* Qb = (unsigned short*)(ws + 23068672);           // 16 MB
    unsigned short* Kb = (unsigned short*)(ws + 39845888);           // 16 MB
    unsigned short* Vb = (unsigned short*)(ws + 56623104);           // 16 MB
    unsigned short* Vt = Xb;   // Xb dead after qkv_gemm; reuse for V^T

    float* tab = (float*)d_out;   // RoPE tables in ctx region (overwritten by attn)

    rope_table_kernel<<<dim3(131072 / 256), 256, 0, stream>>>(tab);
    cast_x_kernel<<<dim3(M_ * HID / 4 / 256), 256, 0, stream>>>(X, Xb);
    cast_wt_kernel<<<dim3(16, 16, 3), 256, 0, stream>>>(Wq, Wk, Wv, Wt);
    qkv_gemm_kernel<<<dim3(HID / BN, M_ / BM, 3), 256, 0, stream>>>(
        Xb, Wt, bq, bk, bv, tab, tab + 131072, (float*)d_out, Qb, Kb, Vb);
    transpose_v_kernel<<<dim3(S_ / 64, B_ * H_), 256, 0, stream>>>(Vb, Vt);
    attn_kernel<<<dim3(H_, S_ / 64, B_), 256, 0, stream>>>(
        Qb, Kb, Vt, mask, (float*)d_out);
}